// Round 2
// baseline (1195.657 us; speedup 1.0000x reference)
//
#include <hip/hip_runtime.h>
#include <hip/hip_bf16.h>
#include <math.h>

// Problem constants
#define BB 128     // batch
#define TT 2048    // time
#define DD 256     // feature dim
#define AA 128     // att dim
#define ROWS (BB*TT)  // 262144

// ws layout (floats):
// [0, 2*ROWS)                       partial[2][ROWS]   (pre-exp logit halves)
// [2*ROWS, 2*ROWS+256)              invZ[BB] (padded)
// [2*ROWS+256, +8*BB*DD)            pout[8][BB][DD]
// total ~3.01 MB — assumed <= ws_size

// ---------------- Phase 1: partial logits -------------------------------
// grid = 1024 blocks: class = blockIdx&1 (a-half), pair = blockIdx>>1 (row set)
// block = 256 threads = 4 waves; wave handles 8 rows; lane <-> a-column.
__global__ __launch_bounds__(256, 2) void k_scores(
    const float* __restrict__ x, const float* __restrict__ w,
    const float* __restrict__ bias, const float* __restrict__ ctx,
    float* __restrict__ partial)
{
    __shared__ float ldsW[DD * 64];  // 64 KB: one a-half of W, [d][a_local]
    const int cls  = blockIdx.x & 1;
    const int pair = blockIdx.x >> 1;      // 0..511
    const int tid  = threadIdx.x;

    // Stage W half into LDS (coalesced 64-float runs)
    for (int i = tid; i < DD * 64; i += 256) {
        int d = i >> 6, a = i & 63;
        ldsW[i] = w[d * AA + cls * 64 + a];
    }
    __syncthreads();

    const int lane = tid & 63;
    const int wv   = tid >> 6;             // wave 0..3
    const int ag   = cls * 64 + lane;      // global a-column
    const float bias_v = bias[ag];
    const float ctx_v  = ctx[ag];

    // 8192 groups of 32 rows; 512 pairs -> 16 iterations each
    for (int g = pair; g < ROWS / 32; g += 512) {
        int row0 = g * 32 + wv * 8;
        row0 = __builtin_amdgcn_readfirstlane(row0);   // force wave-uniform
        const float* xp = x + (size_t)row0 * DD;

        float acc[8] = {0.f,0.f,0.f,0.f,0.f,0.f,0.f,0.f};

        for (int d0 = 0; d0 < DD; d0 += 4) {
            float4 xv[8];
            #pragma unroll
            for (int r = 0; r < 8; ++r)
                xv[r] = *(const float4*)(xp + (size_t)r * DD + d0);
            #pragma unroll
            for (int dd = 0; dd < 4; ++dd) {
                float wval = ldsW[(d0 + dd) * 64 + lane];
                #pragma unroll
                for (int r = 0; r < 8; ++r) {
                    float xs = ((const float*)&xv[r])[dd];
                    acc[r] = fmaf(xs, wval, acc[r]);
                }
            }
        }

        // epilogue: tanh, ctx weight, wave-reduce over 64 a-columns
        #pragma unroll
        for (int r = 0; r < 8; ++r) {
            float t = tanhf(acc[r] + bias_v) * ctx_v;
            #pragma unroll
            for (int off = 32; off > 0; off >>= 1)
                t += __shfl_xor(t, off, 64);
            if (lane == 0)
                partial[(size_t)cls * ROWS + row0 + r] = t;
        }
    }
}

// ---------------- Phase 2: per-batch 1/(sum exp + eps) ------------------
__global__ __launch_bounds__(256) void k_znorm(
    const float* __restrict__ partial, float* __restrict__ invZ)
{
    const int b = blockIdx.x;
    const int tid = threadIdx.x;
    const int lane = tid & 63, wv = tid >> 6;
    __shared__ float red[4];

    float s = 0.f;
    for (int t = tid; t < TT; t += 256) {
        float e = partial[b * TT + t] + partial[ROWS + b * TT + t];
        s += expf(e);
    }
    #pragma unroll
    for (int off = 32; off > 0; off >>= 1)
        s += __shfl_xor(s, off, 64);
    if (lane == 0) red[wv] = s;
    __syncthreads();
    if (tid == 0) {
        float z = red[0] + red[1] + red[2] + red[3];
        invZ[b] = 1.f / (z + 1e-10f);
    }
}

// ---------------- Phase 3: weighted column sum (partials) ---------------
// grid = 128 b * 8 chunks; block = 256 threads (thread <-> d)
__global__ __launch_bounds__(256) void k_wsum(
    const float* __restrict__ x, const float* __restrict__ partial,
    const float* __restrict__ invZ, float* __restrict__ pout)
{
    const int b     = blockIdx.x >> 3;
    const int chunk = blockIdx.x & 7;
    const int d     = threadIdx.x;
    const float iz  = invZ[b];

    float acc = 0.f;
    const int t0 = chunk * 256;
    #pragma unroll 4
    for (int t = t0; t < t0 + 256; ++t) {
        float s  = partial[b * TT + t] + partial[ROWS + b * TT + t];
        float wt = expf(s) * iz;
        acc = fmaf(wt, x[((size_t)(b * TT + t)) * DD + d], acc);
    }
    pout[((size_t)chunk * BB + b) * DD + d] = acc;
}

// ---------------- Phase 4: reduce 8 partials ----------------------------
__global__ __launch_bounds__(256) void k_final(
    const float* __restrict__ pout, float* __restrict__ out)
{
    const int i = blockIdx.x * 256 + threadIdx.x;  // 0..32767
    float s = 0.f;
    #pragma unroll
    for (int c = 0; c < 8; ++c)
        s += pout[(size_t)c * BB * DD + i];
    out[i] = s;
}

extern "C" void kernel_launch(void* const* d_in, const int* in_sizes, int n_in,
                              void* d_out, int out_size, void* d_ws, size_t ws_size,
                              hipStream_t stream)
{
    const float* x    = (const float*)d_in[0];   // [128,2048,256]
    const float* w    = (const float*)d_in[1];   // [256,128]
    const float* bias = (const float*)d_in[2];   // [128]
    const float* ctx  = (const float*)d_in[3];   // [128,1]
    float* out = (float*)d_out;                  // [128,256]

    float* ws      = (float*)d_ws;
    float* partial = ws;                           // 2*ROWS
    float* invZ    = ws + 2 * (size_t)ROWS;        // 128 (padded to 256)
    float* pout    = invZ + 256;                   // 8*BB*DD

    k_scores<<<1024, 256, 0, stream>>>(x, w, bias, ctx, partial);
    k_znorm <<<BB,   256, 0, stream>>>(partial, invZ);
    k_wsum  <<<BB*8, 256, 0, stream>>>(x, partial, invZ, pout);
    k_final <<<BB*DD/256, 256, 0, stream>>>(pout, out);
}

// Round 3
// 683.975 us; speedup vs baseline: 1.7481x; 1.7481x over previous
//
#include <hip/hip_runtime.h>
#include <hip/hip_bf16.h>
#include <math.h>

// Problem constants
#define BB 128     // batch
#define TT 2048    // time
#define DD 256     // feature dim
#define AA 128     // att dim
#define ROWS (BB*TT)  // 262144
#define RT 16      // rows per tile in k_scores2

typedef float __attribute__((address_space(1))) gfloat;
typedef float __attribute__((address_space(3))) sfloat;

// ws layout (floats):
// [0, ROWS)              logits[ROWS]
// [ROWS, 2*ROWS)         expv[ROWS]
// [2*ROWS, 2*ROWS+256)   invZ[BB] (padded)
// [.. +8*BB*DD)          pout[8][BB][DD]
// total ~3.01 MB

// ---------------- Phase 1: logits --------------------------------------
// 512 threads = 8 waves. wave wv: cls = wv&1 (a-half), slc = wv>>1 (d-slice of 64).
// W slice cached in 64 VGPRs per lane. x tiles (16 rows x 256) double-buffered
// in LDS via global_load_lds; inner loop = broadcast ds_read_b128 + reg-W FMA.
__global__ __launch_bounds__(512, 4) void k_scores2(
    const float* __restrict__ x, const float* __restrict__ w,
    const float* __restrict__ bias, const float* __restrict__ ctx,
    float* __restrict__ logits)
{
    __shared__ float ldsX[2][RT][DD];    // 32 KB
    __shared__ float pwave[8][RT][64];   // 32 KB  partial dots per wave
    __shared__ float sred[2][RT];        // per-class row sums

    const int tid  = threadIdx.x;
    const int lane = tid & 63;
    const int wv   = tid >> 6;           // 0..7
    const int cls  = wv & 1;             // a-half
    const int slc  = wv >> 1;            // d-slice 0..3
    const int ag   = cls * 64 + lane;    // this wave's a-column

    // one-time: W slice into registers (coalesced 256 B per instr)
    float wreg[64];
    #pragma unroll
    for (int j = 0; j < 64; ++j)
        wreg[j] = w[(slc * 64 + j) * AA + ag];

    // bias/ctx for BOTH classes (reduction units may differ from own cls)
    const float biasA = bias[lane],      biasB = bias[64 + lane];
    const float ctxA  = ctx[lane],       ctxB  = ctx[64 + lane];

    const int tiles_per_block = (ROWS / RT) / gridDim.x;   // 16384/512 = 32
    const int tile0 = blockIdx.x * tiles_per_block;

    // stage tile (16 KB): 16 wave-chunks of 1 KB; wave wv issues chunks wv*2, wv*2+1
    auto stage = [&](int buf, int tile) {
        const float* src = x + (size_t)tile * RT * DD;
        float* dst = &ldsX[buf][0][0];
        #pragma unroll
        for (int c = 0; c < 2; ++c) {
            int chunk = wv * 2 + c;                       // 0..15
            __builtin_amdgcn_global_load_lds(
                (const gfloat*)(src + chunk * 256 + lane * 4),
                (sfloat*)(dst + chunk * 256), 16, 0, 0);
        }
    };

    int buf = 0;
    stage(0, tile0);
    __syncthreads();                     // drains vmcnt before first use

    for (int i = 0; i < tiles_per_block; ++i) {
        const int tile = tile0 + i;
        if (i + 1 < tiles_per_block) stage(buf ^ 1, tile + 1);

        // compute: acc[r] = sum over this wave's 64-d slice
        const float (*xb)[DD] = ldsX[buf];
        float acc[RT];
        #pragma unroll
        for (int r = 0; r < RT; ++r) acc[r] = 0.f;

        #pragma unroll
        for (int j0 = 0; j0 < 64; j0 += 4) {
            #pragma unroll
            for (int r = 0; r < RT; ++r) {
                float4 xv = *(const float4*)&xb[r][slc * 64 + j0];  // broadcast
                acc[r] = fmaf(xv.x, wreg[j0 + 0], acc[r]);
                acc[r] = fmaf(xv.y, wreg[j0 + 1], acc[r]);
                acc[r] = fmaf(xv.z, wreg[j0 + 2], acc[r]);
                acc[r] = fmaf(xv.w, wreg[j0 + 3], acc[r]);
            }
        }

        #pragma unroll
        for (int r = 0; r < RT; ++r)
            pwave[wv][r][lane] = acc[r];
        __syncthreads();                 // pwave ready (also drains prefetch)

        // reduce 4 d-slices, tanh*ctx, a-reduce: 32 units (cls,row), 4 per wave
        #pragma unroll
        for (int iu = 0; iu < 4; ++iu) {
            const int u    = wv * 4 + iu;        // 0..31
            const int ucls = u >> 4;
            const int urow = u & 15;
            float ps = pwave[0 + ucls][urow][lane]
                     + pwave[2 + ucls][urow][lane]
                     + pwave[4 + ucls][urow][lane]
                     + pwave[6 + ucls][urow][lane];
            const float bv = ucls ? biasB : biasA;
            const float cv = ucls ? ctxB  : ctxA;
            float t = tanhf(ps + bv) * cv;
            #pragma unroll
            for (int off = 32; off > 0; off >>= 1)
                t += __shfl_xor(t, off, 64);
            if (lane == 0) sred[ucls][urow] = t;
        }
        __syncthreads();                 // sred ready

        if (tid < RT)
            logits[(size_t)tile * RT + tid] = sred[0][tid] + sred[1][tid];

        buf ^= 1;
    }
}

// ---------------- Phase 2: exp + per-batch 1/(sum+eps) ------------------
__global__ __launch_bounds__(256) void k_znorm(
    const float* __restrict__ logits, float* __restrict__ expv,
    float* __restrict__ invZ)
{
    const int b = blockIdx.x;
    const int tid = threadIdx.x;
    const int lane = tid & 63, wvv = tid >> 6;
    __shared__ float red[4];

    float s = 0.f;
    for (int t = tid; t < TT; t += 256) {
        float ex = expf(logits[b * TT + t]);
        expv[b * TT + t] = ex;
        s += ex;
    }
    #pragma unroll
    for (int off = 32; off > 0; off >>= 1)
        s += __shfl_xor(s, off, 64);
    if (lane == 0) red[wvv] = s;
    __syncthreads();
    if (tid == 0) {
        float z = red[0] + red[1] + red[2] + red[3];
        invZ[b] = 1.f / (z + 1e-10f);
    }
}

// ---------------- Phase 3: weighted column sum (partials) ---------------
__global__ __launch_bounds__(256) void k_wsum(
    const float* __restrict__ x, const float* __restrict__ expv,
    const float* __restrict__ invZ, float* __restrict__ pout)
{
    const int b     = blockIdx.x >> 3;
    const int chunk = blockIdx.x & 7;
    const int d     = threadIdx.x;
    const float iz  = invZ[b];

    float acc = 0.f;
    const int t0 = chunk * 256;
    #pragma unroll 4
    for (int t = t0; t < t0 + 256; ++t) {
        float wt = expv[b * TT + t] * iz;
        acc = fmaf(wt, x[((size_t)(b * TT + t)) * DD + d], acc);
    }
    pout[((size_t)chunk * BB + b) * DD + d] = acc;
}

// ---------------- Phase 4: reduce 8 partials ----------------------------
__global__ __launch_bounds__(256) void k_final(
    const float* __restrict__ pout, float* __restrict__ out)
{
    const int i = blockIdx.x * 256 + threadIdx.x;  // 0..32767
    float s = 0.f;
    #pragma unroll
    for (int c = 0; c < 8; ++c)
        s += pout[(size_t)c * BB * DD + i];
    out[i] = s;
}

extern "C" void kernel_launch(void* const* d_in, const int* in_sizes, int n_in,
                              void* d_out, int out_size, void* d_ws, size_t ws_size,
                              hipStream_t stream)
{
    const float* x    = (const float*)d_in[0];   // [128,2048,256]
    const float* w    = (const float*)d_in[1];   // [256,128]
    const float* bias = (const float*)d_in[2];   // [128]
    const float* ctx  = (const float*)d_in[3];   // [128,1]
    float* out = (float*)d_out;                  // [128,256]

    float* ws     = (float*)d_ws;
    float* logits = ws;                           // ROWS
    float* expv   = ws + ROWS;                    // ROWS
    float* invZ   = ws + 2 * (size_t)ROWS;        // 128 (padded to 256)
    float* pout   = invZ + 256;                   // 8*BB*DD

    k_scores2<<<512, 512, 0, stream>>>(x, w, bias, ctx, logits);
    k_znorm  <<<BB,  256, 0, stream>>>(logits, expv, invZ);
    k_wsum   <<<BB*8, 256, 0, stream>>>(x, expv, invZ, pout);
    k_final  <<<BB*DD/256, 256, 0, stream>>>(pout, out);
}

// Round 4
// 443.898 us; speedup vs baseline: 2.6935x; 1.5408x over previous
//
#include <hip/hip_runtime.h>
#include <math.h>

#define BB 128
#define TT 2048
#define DD 256
#define AA 128
#define ROWS (BB*TT)   // 262144

typedef __attribute__((ext_vector_type(8))) short bf16x8;
typedef __attribute__((ext_vector_type(4))) float f32x4;

__device__ __forceinline__ unsigned short f2bf(float f) {
    unsigned int u = __builtin_bit_cast(unsigned int, f);
    unsigned int r = (u + 0x7FFFu + ((u >> 16) & 1u)) >> 16;   // RNE
    return (unsigned short)r;
}
__device__ __forceinline__ float bf2f(unsigned short s) {
    unsigned int u = ((unsigned int)s) << 16;
    return __builtin_bit_cast(float, u);
}

// ws layout (floats):
// [0, ROWS)          expv[ROWS]
// [ROWS, ROWS+128)   zsum[BB]  (memset to 0 each launch)
// [ROWS+256, ...)    pout[8][BB][DD]

// ---------------- Phase 1: logits via split-bf16 MFMA -------------------
// 512 thr = 8 waves; wave wv owns a-cols [wv*16, wv*16+16) with W hi/lo in regs.
// x tile = 16 rows x 256 K, fp32->bf16 hi/lo reg-staged into frag-major LDS
// (slot XOR ks swizzle), double buffered. 3 MFMA per K-step (drop lo*lo).
__global__ __launch_bounds__(512, 2) void k_mfma(
    const float* __restrict__ x, const float* __restrict__ w,
    const float* __restrict__ bias, const float* __restrict__ ctx,
    float* __restrict__ expv, float* __restrict__ zsum)
{
    // [buf][1024 frags of 16B]: hi = frags 0..511 (ks*64+slot), lo = 512..1023
    __shared__ bf16x8 ldsx[2][1024];
    __shared__ float pred[8][16];

    const int tid  = threadIdx.x;
    const int lane = tid & 63;
    const int wv   = tid >> 6;

    // ---- W fragments (hi/lo) into registers: one 16-col N-tile per wave ----
    const int colg  = wv * 16 + (lane & 15);
    const int krow0 = (lane >> 4) * 8;
    bf16x8 wh[8], wl[8];
    #pragma unroll
    for (int ks = 0; ks < 8; ++ks) {
        union { bf16x8 v; unsigned short u[8]; } H, L;
        #pragma unroll
        for (int j = 0; j < 8; ++j) {
            float f = w[(ks * 32 + krow0 + j) * AA + colg];
            unsigned short h = f2bf(f);
            H.u[j] = h;
            L.u[j] = f2bf(f - bf2f(h));
        }
        wh[ks] = H.v; wl[ks] = L.v;
    }
    const float bias_l = bias[colg];
    const float ctx_l  = ctx[colg];

    // ---- staging geometry: thread -> (row, 8-k group) of the 16x256 tile ----
    const int srow = tid >> 5;                 // 0..15
    const int kg   = tid & 31;                 // 0..31
    const int sks  = kg >> 2;                  // K-step 0..7
    const int slot = ((kg & 3) << 4) + srow;   // logical frag slot 0..63
    const int wfrag = sks * 64 + (slot ^ sks); // XOR swizzle (bank spread)

    const int ntiles = 32;                     // 16384 tiles / 512 blocks
    const int tile0  = blockIdx.x * ntiles;

    float ld[8];
    auto issue_loads = [&](int tile) {
        const float* src = x + (size_t)tile * (16 * DD) + srow * DD + kg * 8;
        float4 a = *(const float4*)(src);
        float4 b = *(const float4*)(src + 4);
        ld[0]=a.x; ld[1]=a.y; ld[2]=a.z; ld[3]=a.w;
        ld[4]=b.x; ld[5]=b.y; ld[6]=b.z; ld[7]=b.w;
    };
    auto write_lds = [&](int buf) {
        union { bf16x8 v; unsigned short u[8]; } H, L;
        #pragma unroll
        for (int j = 0; j < 8; ++j) {
            unsigned short h = f2bf(ld[j]);
            H.u[j] = h;
            L.u[j] = f2bf(ld[j] - bf2f(h));
        }
        ldsx[buf][wfrag]       = H.v;
        ldsx[buf][512 + wfrag] = L.v;
    };

    issue_loads(tile0);
    write_lds(0);
    __syncthreads();

    for (int i = 0; i < ntiles; ++i) {
        const int tile = tile0 + i;
        if (i + 1 < ntiles) issue_loads(tile + 1);   // prefetch into regs

        // ---- MFMA over K: acc covers 16 rows x this wave's 16 cols ----
        const int buf = i & 1;
        f32x4 acc = {0.f, 0.f, 0.f, 0.f};
        #pragma unroll
        for (int ks = 0; ks < 8; ++ks) {
            const int rf = ks * 64 + (lane ^ ks);
            bf16x8 ah = ldsx[buf][rf];
            bf16x8 al = ldsx[buf][512 + rf];
            acc = __builtin_amdgcn_mfma_f32_16x16x32_bf16(ah, wh[ks], acc, 0, 0, 0);
            acc = __builtin_amdgcn_mfma_f32_16x16x32_bf16(al, wh[ks], acc, 0, 0, 0);
            acc = __builtin_amdgcn_mfma_f32_16x16x32_bf16(ah, wl[ks], acc, 0, 0, 0);
        }

        // ---- epilogue: tanh*ctx, reduce over this wave's 16 cols ----
        #pragma unroll
        for (int r = 0; r < 4; ++r) {
            float v = tanhf(acc[r] + bias_l) * ctx_l;
            v += __shfl_xor(v, 1, 64);
            v += __shfl_xor(v, 2, 64);
            v += __shfl_xor(v, 4, 64);
            v += __shfl_xor(v, 8, 64);
            if ((lane & 15) == 0) pred[wv][(lane >> 4) * 4 + r] = v;
        }
        __syncthreads();                         // pred ready; old-buf reads done

        if (i + 1 < ntiles) write_lds(buf ^ 1);  // convert + store next tile

        if (tid < 16) {                          // one thread per row
            float s = pred[0][tid] + pred[1][tid] + pred[2][tid] + pred[3][tid]
                    + pred[4][tid] + pred[5][tid] + pred[6][tid] + pred[7][tid];
            float e = expf(s);
            expv[(size_t)tile * 16 + tid] = e;
            float t = e;
            t += __shfl_xor(t, 1, 64);
            t += __shfl_xor(t, 2, 64);
            t += __shfl_xor(t, 4, 64);
            t += __shfl_xor(t, 8, 64);
            if (tid == 0) atomicAdd(&zsum[tile >> 7], t);
        }
        __syncthreads();                         // next buf written; pred free
    }
}

// ---------------- Phase 2: weighted column sum (partials) ---------------
__global__ __launch_bounds__(256) void k_wsum(
    const float* __restrict__ x, const float* __restrict__ expv,
    const float* __restrict__ zsum, float* __restrict__ pout)
{
    const int b     = blockIdx.x >> 3;
    const int chunk = blockIdx.x & 7;
    const int d     = threadIdx.x;
    const float iz  = 1.f / (zsum[b] + 1e-10f);

    float acc = 0.f;
    const int t0 = chunk * 256;
    #pragma unroll 4
    for (int t = t0; t < t0 + 256; ++t) {
        float wt = expv[b * TT + t] * iz;
        acc = fmaf(wt, x[((size_t)(b * TT + t)) * DD + d], acc);
    }
    pout[((size_t)chunk * BB + b) * DD + d] = acc;
}

// ---------------- Phase 3: reduce 8 partials ----------------------------
__global__ __launch_bounds__(256) void k_final(
    const float* __restrict__ pout, float* __restrict__ out)
{
    const int i = blockIdx.x * 256 + threadIdx.x;  // 0..32767
    float s = 0.f;
    #pragma unroll
    for (int c = 0; c < 8; ++c)
        s += pout[(size_t)c * BB * DD + i];
    out[i] = s;
}

extern "C" void kernel_launch(void* const* d_in, const int* in_sizes, int n_in,
                              void* d_out, int out_size, void* d_ws, size_t ws_size,
                              hipStream_t stream)
{
    const float* x    = (const float*)d_in[0];   // [128,2048,256]
    const float* w    = (const float*)d_in[1];   // [256,128]
    const float* bias = (const float*)d_in[2];   // [128]
    const float* ctx  = (const float*)d_in[3];   // [128,1]
    float* out = (float*)d_out;                  // [128,256]

    float* ws   = (float*)d_ws;
    float* expv = ws;                            // ROWS
    float* zsum = ws + ROWS;                     // 128 (padded to 256)
    float* pout = zsum + 256;                    // 8*BB*DD

    hipMemsetAsync(zsum, 0, 128 * sizeof(float), stream);
    k_mfma <<<512, 512, 0, stream>>>(x, w, bias, ctx, expv, zsum);
    k_wsum <<<BB*8, 256, 0, stream>>>(x, expv, zsum, pout);
    k_final<<<BB*DD/256, 256, 0, stream>>>(pout, out);
}